// Round 1
// baseline (471.933 us; speedup 1.0000x reference)
//
#include <hip/hip_runtime.h>

// Problem constants: L=4096 time steps, N=64 state dim, B=64 batch.
#define TN 64
#define TB 64
#define TL 4096
#define CH 16          // chunk length
#define CN 256         // number of chunks = TL/CH (one per CU)
#define SD 68          // LDS row stride (64 + 4 pad, keeps 16B alignment)

// ---------------------------------------------------------------------------
// Phase 1: per chunk c, compute (backward over the chunk)
//   P_c = A[hi] @ ... @ A[lo]                 (N x N)
//   V_c = sum_t (A[hi]..A[t+1]) b_t inp_t^T   (N x B)
// using suffix product S and the rank-1 structure of u_t = b_t * inp_t.
// ---------------------------------------------------------------------------
__global__ __launch_bounds__(256)
void hippo_phase1(const float* __restrict__ inp, const float* __restrict__ Ag,
                  const float* __restrict__ Bst,
                  float* __restrict__ Pout, float* __restrict__ Vout)
{
    __shared__ float S[TN * SD];        // S[n][k], padded stride
    __shared__ float Ab[2][TN * SD];    // A[t] native [k][j], double buffered
    __shared__ float wbuf[TN];
    __shared__ float btl[TN];
    __shared__ float itl[TB];

    const int tid  = threadIdx.x;
    const int c    = blockIdx.x;
    const int t0   = c * CH;
    const int lane = tid & 63;
    const int n0   = (tid >> 6) * 16;

    // S = I
#pragma unroll
    for (int q = 0; q < 16; ++q) {
        int f = tid + q * 256;
        int n = f >> 6, k = f & 63;
        S[n * SD + k] = (n == k) ? 1.0f : 0.0f;
    }

    float vacc[16];
#pragma unroll
    for (int i = 0; i < 16; ++i) vacc[i] = 0.0f;

    int t = t0 + CH - 1;
    float4 pre[4];
    {
        const float4* Ap = (const float4*)(Ag + (size_t)t * 4096);
#pragma unroll
        for (int q = 0; q < 4; ++q) pre[q] = Ap[tid + q * 256];
    }
#pragma unroll
    for (int q = 0; q < 4; ++q) {
        int f = (tid + q * 256) * 4;
        int r = f >> 6, c0 = f & 63;
        *(float4*)&Ab[0][r * SD + c0] = pre[q];
    }
    int bufi = 0;

    for (; t >= t0; --t) {
        if (tid < 64) {
            btl[tid] = Bst[(size_t)t * 64 + tid];
            itl[tid] = inp[(size_t)t * 64 + tid];
        }
        __syncthreads();   // A, btl, itl ready

        // w = S * b_t (S BEFORE this step's update). 4 threads per row.
        {
            int t4 = tid & 3, wn = tid >> 2;
            int k0 = t4 * 16;
            float p = 0.0f;
#pragma unroll
            for (int i = 0; i < 16; ++i) p += S[wn * SD + k0 + i] * btl[k0 + i];
            p += __shfl_xor(p, 1);
            p += __shfl_xor(p, 2);
            if (t4 == 0) wbuf[wn] = p;
        }
        // prefetch next A into registers
        if (t > t0) {
            const float4* Ap = (const float4*)(Ag + (size_t)(t - 1) * 4096);
#pragma unroll
            for (int q = 0; q < 4; ++q) pre[q] = Ap[tid + q * 256];
        }
        __syncthreads();   // wbuf ready

        // V += w  outer  inp_t
        {
            float ib = itl[lane];
#pragma unroll
            for (int i = 0; i < 16; ++i) vacc[i] += wbuf[n0 + i] * ib;
        }

        // S_new[n][j] = sum_k S[n][k] * A[k][j]; lane = j, 16 rows per thread
        float acc[16];
#pragma unroll
        for (int i = 0; i < 16; ++i) acc[i] = 0.0f;
#pragma unroll 4
        for (int kb = 0; kb < 64; kb += 4) {
            float a0 = Ab[bufi][(kb + 0) * SD + lane];
            float a1 = Ab[bufi][(kb + 1) * SD + lane];
            float a2 = Ab[bufi][(kb + 2) * SD + lane];
            float a3 = Ab[bufi][(kb + 3) * SD + lane];
#pragma unroll
            for (int i = 0; i < 16; ++i) {
                float4 s4 = *(const float4*)&S[(n0 + i) * SD + kb];
                acc[i] = fmaf(s4.x, a0, acc[i]);
                acc[i] = fmaf(s4.y, a1, acc[i]);
                acc[i] = fmaf(s4.z, a2, acc[i]);
                acc[i] = fmaf(s4.w, a3, acc[i]);
            }
        }
        __syncthreads();   // all S reads done

#pragma unroll
        for (int i = 0; i < 16; ++i) S[(n0 + i) * SD + lane] = acc[i];
        if (t > t0) {
            bufi ^= 1;
#pragma unroll
            for (int q = 0; q < 4; ++q) {
                int f = (tid + q * 256) * 4;
                int r = f >> 6, c0 = f & 63;
                *(float4*)&Ab[bufi][r * SD + c0] = pre[q];
            }
        }
        // next-iteration top barrier makes these writes visible
    }
    __syncthreads();

    // write P (=S) and V
    {
        float* Pd = Pout + (size_t)c * 4096;
#pragma unroll
        for (int q = 0; q < 4; ++q) {
            int f = (tid + q * 256) * 4;
            int r = f >> 6, c0 = f & 63;
            *(float4*)(Pd + f) = *(const float4*)&S[r * SD + c0];
        }
        float* Vd = Vout + (size_t)c * 4096;
#pragma unroll
        for (int i = 0; i < 16; ++i) Vd[(n0 + i) * 64 + lane] = vacc[i];
    }
}

// ---------------------------------------------------------------------------
// Phase 2: one Kogge-Stone round. (P,V)_c <- (P_c@P_{c-s}, P_c@V_{c-s}+V_c)
// ---------------------------------------------------------------------------
__global__ __launch_bounds__(256)
void hippo_scan(const float* __restrict__ Pold, const float* __restrict__ Vold,
                float* __restrict__ Pnew, float* __restrict__ Vnew, int s)
{
    const int c   = blockIdx.x;
    const int tid = threadIdx.x;
    if (c < s) {
        const float4* ps = (const float4*)(Pold + (size_t)c * 4096);
        float4*       pd = (float4*)(Pnew + (size_t)c * 4096);
        const float4* vs = (const float4*)(Vold + (size_t)c * 4096);
        float4*       vd = (float4*)(Vnew + (size_t)c * 4096);
#pragma unroll
        for (int q = 0; q < 4; ++q) {
            pd[tid + q * 256] = ps[tid + q * 256];
            vd[tid + q * 256] = vs[tid + q * 256];
        }
        return;
    }
    __shared__ float Pc[TN * SD];   // broadcast operand rows n
    __shared__ float Pp[TN * SD];   // rows k, lane j
    __shared__ float Vp[TN * SD];   // rows k, lane b
    const float* pc = Pold + (size_t)c * 4096;
    const float* pp = Pold + (size_t)(c - s) * 4096;
    const float* vp = Vold + (size_t)(c - s) * 4096;
#pragma unroll
    for (int q = 0; q < 4; ++q) {
        int f = (tid + q * 256) * 4;
        int r = f >> 6, c0 = f & 63;
        *(float4*)&Pc[r * SD + c0] = *(const float4*)(pc + f);
        *(float4*)&Pp[r * SD + c0] = *(const float4*)(pp + f);
        *(float4*)&Vp[r * SD + c0] = *(const float4*)(vp + f);
    }
    __syncthreads();

    const int lane = tid & 63, n0 = (tid >> 6) * 16;
    float accP[16], accV[16];
#pragma unroll
    for (int i = 0; i < 16; ++i) { accP[i] = 0.0f; accV[i] = 0.0f; }
#pragma unroll 4
    for (int kb = 0; kb < 64; kb += 4) {
        float p0 = Pp[(kb + 0) * SD + lane];
        float p1 = Pp[(kb + 1) * SD + lane];
        float p2 = Pp[(kb + 2) * SD + lane];
        float p3 = Pp[(kb + 3) * SD + lane];
        float v0 = Vp[(kb + 0) * SD + lane];
        float v1 = Vp[(kb + 1) * SD + lane];
        float v2 = Vp[(kb + 2) * SD + lane];
        float v3 = Vp[(kb + 3) * SD + lane];
#pragma unroll
        for (int i = 0; i < 16; ++i) {
            float4 r4 = *(const float4*)&Pc[(n0 + i) * SD + kb];
            accP[i] = fmaf(r4.x, p0, accP[i]);
            accP[i] = fmaf(r4.y, p1, accP[i]);
            accP[i] = fmaf(r4.z, p2, accP[i]);
            accP[i] = fmaf(r4.w, p3, accP[i]);
            accV[i] = fmaf(r4.x, v0, accV[i]);
            accV[i] = fmaf(r4.y, v1, accV[i]);
            accV[i] = fmaf(r4.z, v2, accV[i]);
            accV[i] = fmaf(r4.w, v3, accV[i]);
        }
    }
    const float* vc = Vold + (size_t)c * 4096;
    float* pn = Pnew + (size_t)c * 4096;
    float* vn = Vnew + (size_t)c * 4096;
#pragma unroll
    for (int i = 0; i < 16; ++i) {
        int idx = (n0 + i) * 64 + lane;
        pn[idx] = accP[i];
        vn[idx] = accV[i] + vc[idx];
    }
}

// ---------------------------------------------------------------------------
// Phase 3: run chunk forward from entering state E_{c-1}, write all outputs.
// X[n][b] in LDS; out[t][b][n] written via LDS transpose (coalesced 1KB/wave).
// ---------------------------------------------------------------------------
__global__ __launch_bounds__(256)
void hippo_phase3(const float* __restrict__ inp, const float* __restrict__ Ag,
                  const float* __restrict__ Bst, const float* __restrict__ Epre,
                  float* __restrict__ out)
{
    __shared__ float X[TN * SD];
    __shared__ float Ab[2][TN * SD];
    __shared__ float btl[TN];
    __shared__ float itl[TB];

    const int tid  = threadIdx.x;
    const int c    = blockIdx.x;
    const int t0   = c * CH;
    const int lane = tid & 63;
    const int n0   = (tid >> 6) * 16;

    if (c == 0) {
#pragma unroll
        for (int q = 0; q < 16; ++q) {
            int f = tid + q * 256;
            X[(f >> 6) * SD + (f & 63)] = 0.0f;
        }
    } else {
        const float* e = Epre + (size_t)(c - 1) * 4096;
#pragma unroll
        for (int q = 0; q < 4; ++q) {
            int f = (tid + q * 256) * 4;
            int r = f >> 6, c0 = f & 63;
            *(float4*)&X[r * SD + c0] = *(const float4*)(e + f);
        }
    }

    float4 pre[4];
    {
        const float4* Ap = (const float4*)(Ag + (size_t)t0 * 4096);
#pragma unroll
        for (int q = 0; q < 4; ++q) pre[q] = Ap[tid + q * 256];
    }
#pragma unroll
    for (int q = 0; q < 4; ++q) {
        int f = (tid + q * 256) * 4;
        int r = f >> 6, c0 = f & 63;
        *(float4*)&Ab[0][r * SD + c0] = pre[q];
    }
    int bufi = 0;

    for (int t = t0; t < t0 + CH; ++t) {
        if (tid < 64) {
            btl[tid] = Bst[(size_t)t * 64 + tid];
            itl[tid] = inp[(size_t)t * 64 + tid];
        }
        __syncthreads();   // A, btl, itl, X ready

        float acc[16];
        {
            float ib = itl[lane];
#pragma unroll
            for (int i = 0; i < 16; ++i) acc[i] = btl[n0 + i] * ib;
        }
        if (t + 1 < t0 + CH) {
            const float4* An = (const float4*)(Ag + (size_t)(t + 1) * 4096);
#pragma unroll
            for (int q = 0; q < 4; ++q) pre[q] = An[tid + q * 256];
        }
        // X_new[n][b] = sum_k A[n][k] X[k][b] + b_t[n] inp_t[b]; lane = b
#pragma unroll 4
        for (int kb = 0; kb < 64; kb += 4) {
            float x0 = X[(kb + 0) * SD + lane];
            float x1 = X[(kb + 1) * SD + lane];
            float x2 = X[(kb + 2) * SD + lane];
            float x3 = X[(kb + 3) * SD + lane];
#pragma unroll
            for (int i = 0; i < 16; ++i) {
                float4 a4 = *(const float4*)&Ab[bufi][(n0 + i) * SD + kb];
                acc[i] = fmaf(a4.x, x0, acc[i]);
                acc[i] = fmaf(a4.y, x1, acc[i]);
                acc[i] = fmaf(a4.z, x2, acc[i]);
                acc[i] = fmaf(a4.w, x3, acc[i]);
            }
        }
        __syncthreads();   // all X reads done

#pragma unroll
        for (int i = 0; i < 16; ++i) X[(n0 + i) * SD + lane] = acc[i];
        if (t + 1 < t0 + CH) {
            bufi ^= 1;
#pragma unroll
            for (int q = 0; q < 4; ++q) {
                int f = (tid + q * 256) * 4;
                int r = f >> 6, c0 = f & 63;
                *(float4*)&Ab[bufi][r * SD + c0] = pre[q];
            }
        }
        __syncthreads();   // X_new ready

        // out[t][b][n]: coalesced via LDS transpose
        float* od = out + (size_t)t * 4096;
#pragma unroll
        for (int q = 0; q < 4; ++q) {
            int f  = (tid + q * 256) * 4;
            int bb = f >> 6, nn = f & 63;
            float4 o;
            o.x = X[(nn + 0) * SD + bb];
            o.y = X[(nn + 1) * SD + bb];
            o.z = X[(nn + 2) * SD + bb];
            o.w = X[(nn + 3) * SD + bb];
            *(float4*)(od + f) = o;
        }
    }
}

extern "C" void kernel_launch(void* const* d_in, const int* in_sizes, int n_in,
                              void* d_out, int out_size, void* d_ws, size_t ws_size,
                              hipStream_t stream)
{
    const float* inp = (const float*)d_in[0];   // (L, B)
    const float* A   = (const float*)d_in[1];   // (L, N, N)
    const float* Bst = (const float*)d_in[2];   // (L, N)
    float* out = (float*)d_out;                  // (L, B, N)
    float* ws  = (float*)d_ws;                   // needs 4 * CN * 4096 floats = 16 MB

    float* P0 = ws;
    float* P1 = ws + (size_t)CN * 4096;
    float* V0 = ws + (size_t)2 * CN * 4096;
    float* V1 = ws + (size_t)3 * CN * 4096;

    hippo_phase1<<<CN, 256, 0, stream>>>(inp, A, Bst, P0, V0);

    const float* po = P0; const float* vo = V0;
    float* pn = P1; float* vn = V1;
    for (int r = 0; r < 8; ++r) {
        hippo_scan<<<CN, 256, 0, stream>>>(po, vo, pn, vn, 1 << r);
        const float* tp = pn; const float* tv = vn;
        pn = (float*)po; vn = (float*)vo;
        po = tp; vo = tv;
    }
    // after 8 rounds the inclusive prefix lives in (P0, V0)
    hippo_phase3<<<CN, 256, 0, stream>>>(inp, A, Bst, V0, out);
}

// Round 2
// 234.456 us; speedup vs baseline: 2.0129x; 2.0129x over previous
//
#include <hip/hip_runtime.h>

// L=4096, N=B=64. CH=8 -> CN=512 chunks (2 WG/CU on 256 CUs).
#define TL 4096
#define NB 64
#define CH 8
#define CN 512
#define AS 72          // LDS row stride (bf16 elems): 144 B = 9 x 16B groups (odd -> conflict-free b128)

typedef __attribute__((ext_vector_type(8))) short short8;   // 8 x bf16 MFMA frag
typedef __attribute__((ext_vector_type(4))) short short4v;  // 4 x bf16 (b64 store)
typedef __attribute__((ext_vector_type(4))) float floatx4;  // MFMA acc

__device__ inline floatx4 mfma_bf16(short8 a, short8 b, floatx4 c) {
    return __builtin_amdgcn_mfma_f32_16x16x32_bf16(a, b, c, 0, 0, 0);
}

// fp32 -> (hi, lo) bf16 pair, RNE both. x ~= hi + lo to ~2^-17 rel.
__device__ inline void split_bf16(float x, short& h, short& l) {
    union { float f; unsigned u; } v; v.f = x;
    unsigned uh = v.u + 0x7FFFu + ((v.u >> 16) & 1u);
    h = (short)(uh >> 16);
    union { unsigned u; float f; } hv; hv.u = ((unsigned)(unsigned short)h) << 16;
    float r = x - hv.f;
    union { float f; unsigned u; } rv; rv.f = r;
    unsigned ul = rv.u + 0x7FFFu + ((rv.u >> 16) & 1u);
    l = (short)(ul >> 16);
}

// ---------------------------------------------------------------------------
// Phase 1 (forward): per chunk c, S <- A[t]*S (S0=I), V <- A[t]*V + b_t (x) i_t.
// Emits PT[c] = S^T, VT[c] = V^T (fp32, row-major in the transposed index).
// LDS: A row-major [m][k] (Aop frags natural b128); S,V transposed [col][k]
// (Bop frags natural b128; C-layout writeback = contiguous b64).
// ---------------------------------------------------------------------------
__global__ __launch_bounds__(256, 2)
void hippo_phase1(const float* __restrict__ inp, const float* __restrict__ Ag,
                  const float* __restrict__ Bst,
                  float* __restrict__ PT, float* __restrict__ VT)
{
    __shared__ short Ah[NB][AS], Al[NB][AS];
    __shared__ short SBh[NB][AS], SBl[NB][AS];
    __shared__ short VBh[NB][AS], VBl[NB][AS];
    __shared__ float btl[NB], itl[NB];

    const int tid  = threadIdx.x;
    const int c    = blockIdx.x;
    const int t0   = c * CH;
    const int w    = tid >> 6, lane = tid & 63;
    const int quad = lane >> 4, l15 = lane & 15;

    // SB = I (bf16(1.0) = 0x3F80), VB = 0
#pragma unroll
    for (int q = 0; q < 16; ++q) {
        int f = tid + q * 256;
        int n = f >> 6, k = f & 63;
        SBh[n][k] = (n == k) ? (short)0x3F80 : (short)0;
        SBl[n][k] = 0; VBh[n][k] = 0; VBl[n][k] = 0;
    }

    float4 pre[4];
    {
        const float4* Ap = (const float4*)(Ag + (size_t)t0 * 4096);
#pragma unroll
        for (int q = 0; q < 4; ++q) pre[q] = Ap[tid + q * 256];
    }

    floatx4 accS[4], accV[4];

    for (int s = 0; s < CH; ++s) {
        int t = t0 + s;
        // stage A[t] (split) from prefetched regs: row m, cols k0..k0+3
#pragma unroll
        for (int q = 0; q < 4; ++q) {
            int f = tid + q * 256;
            int m = f >> 4, k0 = (f & 15) * 4;
            float vv[4] = {pre[q].x, pre[q].y, pre[q].z, pre[q].w};
            short4v h4, l4;
#pragma unroll
            for (int r = 0; r < 4; ++r) { short hh, ll; split_bf16(vv[r], hh, ll); h4[r]=hh; l4[r]=ll; }
            *(short4v*)&Ah[m][k0] = h4;
            *(short4v*)&Al[m][k0] = l4;
        }
        if (tid < 64) { btl[tid] = Bst[(size_t)t*64 + tid]; itl[tid] = inp[(size_t)t*64 + tid]; }
        if (s + 1 < CH) {
            const float4* Ap = (const float4*)(Ag + (size_t)(t+1) * 4096);
#pragma unroll
            for (int q = 0; q < 4; ++q) pre[q] = Ap[tid + q * 256];
        }
        __syncthreads();   // A, btl/itl, prev SB/VB visible

#pragma unroll
        for (int ni = 0; ni < 4; ++ni) {
            float ib = itl[16*ni + l15];
#pragma unroll
            for (int r = 0; r < 4; ++r) {
                accS[ni][r] = 0.0f;
                accV[ni][r] = btl[16*w + 4*quad + r] * ib;   // u_t = b_t (x) i_t in C-layout
            }
        }
#pragma unroll
        for (int kc = 0; kc < 2; ++kc) {
            int ko = 32*kc + 8*quad;
            short8 aH = *(const short8*)&Ah[16*w + l15][ko];
            short8 aL = *(const short8*)&Al[16*w + l15][ko];
#pragma unroll
            for (int ni = 0; ni < 4; ++ni) {
                int n = 16*ni + l15;
                short8 sH = *(const short8*)&SBh[n][ko];
                short8 sL = *(const short8*)&SBl[n][ko];
                accS[ni] = mfma_bf16(aH, sH, accS[ni]);
                accS[ni] = mfma_bf16(aH, sL, accS[ni]);
                accS[ni] = mfma_bf16(aL, sH, accS[ni]);
                short8 vH = *(const short8*)&VBh[n][ko];
                short8 vL = *(const short8*)&VBl[n][ko];
                accV[ni] = mfma_bf16(aH, vH, accV[ni]);
                accV[ni] = mfma_bf16(aH, vL, accV[ni]);
                accV[ni] = mfma_bf16(aL, vH, accV[ni]);
            }
        }
        __syncthreads();   // all SB/VB reads done

        if (s + 1 < CH) {
            // C-layout -> transposed state layout: contiguous b64 per lane
#pragma unroll
            for (int ni = 0; ni < 4; ++ni) {
                int cc = 16*ni + l15, r0 = 16*w + 4*quad;
                short4v h4, l4;
#pragma unroll
                for (int r = 0; r < 4; ++r) { short hh,ll; split_bf16(accS[ni][r],hh,ll); h4[r]=hh; l4[r]=ll; }
                *(short4v*)&SBh[cc][r0] = h4; *(short4v*)&SBl[cc][r0] = l4;
#pragma unroll
                for (int r = 0; r < 4; ++r) { short hh,ll; split_bf16(accV[ni][r],hh,ll); h4[r]=hh; l4[r]=ll; }
                *(short4v*)&VBh[cc][r0] = h4; *(short4v*)&VBl[cc][r0] = l4;
            }
        }
    }
    // final S, V still in acc regs (fp32): store transposed, coalesced float4
#pragma unroll
    for (int ni = 0; ni < 4; ++ni) {
        int cc = 16*ni + l15, r0 = 16*w + 4*quad;
        *(floatx4*)(PT + (size_t)c*4096 + cc*64 + r0) = accS[ni];
        *(floatx4*)(VT + (size_t)c*4096 + cc*64 + r0) = accV[ni];
    }
}

// ---------------------------------------------------------------------------
// Phase 2: Kogge-Stone round. (P,V)_c <- (Pc@Pp, Pc@Vp + Vc), p = c - s.
// Global P/V stored transposed (PT/VT). Pc must be re-transposed into
// row-major Aop LDS (cold path, once per round).
// ---------------------------------------------------------------------------
__global__ __launch_bounds__(256, 2)
void hippo_scan(const float* __restrict__ PTs, const float* __restrict__ VTs,
                float* __restrict__ PTd, float* __restrict__ VTd,
                int s, int need_p)
{
    const int c = blockIdx.x, tid = threadIdx.x;
    if (c < s) {
        const float4* vs = (const float4*)(VTs + (size_t)c*4096);
        float4*       vd = (float4*)(VTd + (size_t)c*4096);
#pragma unroll
        for (int q = 0; q < 4; ++q) vd[tid + q*256] = vs[tid + q*256];
        if (need_p) {
            const float4* ps = (const float4*)(PTs + (size_t)c*4096);
            float4*       pd = (float4*)(PTd + (size_t)c*4096);
#pragma unroll
            for (int q = 0; q < 4; ++q) pd[tid + q*256] = ps[tid + q*256];
        }
        return;
    }
    __shared__ short PAh[NB][AS], PAl[NB][AS];   // Pc row-major (Aop)
    __shared__ short PBh[NB][AS], PBl[NB][AS];   // Pp^T (Bop)
    __shared__ short VBh[NB][AS], VBl[NB][AS];   // Vp^T (Bop)
    const float* ptc = PTs + (size_t)c*4096;
    const float* ptp = PTs + (size_t)(c - s)*4096;
    const float* vtp = VTs + (size_t)(c - s)*4096;

    // Pc: PT[k][m0..3] float4 -> scattered b16 into rows m0..m0+3 (transpose)
#pragma unroll
    for (int q = 0; q < 4; ++q) {
        int f = tid + q*256;
        int k = f & 63, m0 = (f >> 6) * 4;
        float4 v = *(const float4*)(ptc + k*64 + m0);
        float vv[4] = {v.x, v.y, v.z, v.w};
#pragma unroll
        for (int r = 0; r < 4; ++r) { short hh,ll; split_bf16(vv[r],hh,ll); PAh[m0+r][k]=hh; PAl[m0+r][k]=ll; }
    }
    // Pp^T, Vp^T: direct row copy (split), contiguous b64
#pragma unroll
    for (int q = 0; q < 4; ++q) {
        int f = tid + q*256;
        int n = f >> 4, k0 = (f & 15) * 4;
        short4v h4, l4;
        if (need_p) {
            float4 p = *(const float4*)(ptp + n*64 + k0);
            float pa[4] = {p.x,p.y,p.z,p.w};
#pragma unroll
            for (int r=0;r<4;++r){short hh,ll;split_bf16(pa[r],hh,ll);h4[r]=hh;l4[r]=ll;}
            *(short4v*)&PBh[n][k0] = h4; *(short4v*)&PBl[n][k0] = l4;
        }
        float4 vv = *(const float4*)(vtp + n*64 + k0);
        float va[4] = {vv.x,vv.y,vv.z,vv.w};
#pragma unroll
        for (int r=0;r<4;++r){short hh,ll;split_bf16(va[r],hh,ll);h4[r]=hh;l4[r]=ll;}
        *(short4v*)&VBh[n][k0] = h4; *(short4v*)&VBl[n][k0] = l4;
    }
    __syncthreads();

    const int w = tid>>6, lane = tid&63, quad = lane>>4, l15 = lane&15;
    const float* vtc = VTs + (size_t)c*4096;
    floatx4 accP[4], accV[4];
#pragma unroll
    for (int ni = 0; ni < 4; ++ni) {
        int cc = 16*ni + l15, r0 = 16*w + 4*quad;
        float4 vc = *(const float4*)(vtc + cc*64 + r0);   // Vc in C-layout
        accV[ni][0]=vc.x; accV[ni][1]=vc.y; accV[ni][2]=vc.z; accV[ni][3]=vc.w;
        accP[ni][0]=accP[ni][1]=accP[ni][2]=accP[ni][3]=0.0f;
    }
#pragma unroll
    for (int kc = 0; kc < 2; ++kc) {
        int ko = 32*kc + 8*quad;
        short8 aH = *(const short8*)&PAh[16*w + l15][ko];
        short8 aL = *(const short8*)&PAl[16*w + l15][ko];
#pragma unroll
        for (int ni = 0; ni < 4; ++ni) {
            int n = 16*ni + l15;
            short8 vH = *(const short8*)&VBh[n][ko];
            short8 vL = *(const short8*)&VBl[n][ko];
            accV[ni] = mfma_bf16(aH, vH, accV[ni]);
            accV[ni] = mfma_bf16(aH, vL, accV[ni]);
            accV[ni] = mfma_bf16(aL, vH, accV[ni]);
            if (need_p) {
                short8 pH = *(const short8*)&PBh[n][ko];
                short8 pL = *(const short8*)&PBl[n][ko];
                accP[ni] = mfma_bf16(aH, pH, accP[ni]);
                accP[ni] = mfma_bf16(aH, pL, accP[ni]);
                accP[ni] = mfma_bf16(aL, pH, accP[ni]);
            }
        }
    }
#pragma unroll
    for (int ni = 0; ni < 4; ++ni) {
        int cc = 16*ni + l15, r0 = 16*w + 4*quad;
        *(floatx4*)(VTd + (size_t)c*4096 + cc*64 + r0) = accV[ni];
        if (need_p) *(floatx4*)(PTd + (size_t)c*4096 + cc*64 + r0) = accP[ni];
    }
}

// ---------------------------------------------------------------------------
// Phase 3: x <- A[t] x + u_t from entering state E_{c-1} = VT_prefix[c-1];
// write out[t][b][n] as coalesced float4 straight from C-layout regs.
// ---------------------------------------------------------------------------
__global__ __launch_bounds__(256, 2)
void hippo_phase3(const float* __restrict__ inp, const float* __restrict__ Ag,
                  const float* __restrict__ Bst, const float* __restrict__ VTpre,
                  float* __restrict__ out)
{
    __shared__ short Ah[NB][AS], Al[NB][AS];
    __shared__ short XBh[NB][AS], XBl[NB][AS];
    __shared__ float btl[NB], itl[NB];

    const int tid = threadIdx.x, c = blockIdx.x, t0 = c * CH;
    const int w = tid>>6, lane = tid&63, quad = lane>>4, l15 = lane&15;

    if (c == 0) {
#pragma unroll
        for (int q = 0; q < 16; ++q) { int f = tid + q*256; XBh[f>>6][f&63] = 0; XBl[f>>6][f&63] = 0; }
    } else {
        const float* e = VTpre + (size_t)(c-1)*4096;
#pragma unroll
        for (int q = 0; q < 4; ++q) {
            int f = tid + q*256; int b = f>>4, k0 = (f&15)*4;
            float4 v = *(const float4*)(e + b*64 + k0);
            float va[4] = {v.x,v.y,v.z,v.w};
            short4v h4, l4;
#pragma unroll
            for (int r=0;r<4;++r){short hh,ll;split_bf16(va[r],hh,ll);h4[r]=hh;l4[r]=ll;}
            *(short4v*)&XBh[b][k0] = h4; *(short4v*)&XBl[b][k0] = l4;
        }
    }
    float4 pre[4];
    {
        const float4* Ap = (const float4*)(Ag + (size_t)t0 * 4096);
#pragma unroll
        for (int q = 0; q < 4; ++q) pre[q] = Ap[tid + q * 256];
    }
    floatx4 acc[4];
    for (int s = 0; s < CH; ++s) {
        int t = t0 + s;
#pragma unroll
        for (int q = 0; q < 4; ++q) {
            int f = tid + q*256; int m = f>>4, k0 = (f&15)*4;
            float vv[4] = {pre[q].x,pre[q].y,pre[q].z,pre[q].w};
            short4v h4, l4;
#pragma unroll
            for (int r=0;r<4;++r){short hh,ll;split_bf16(vv[r],hh,ll);h4[r]=hh;l4[r]=ll;}
            *(short4v*)&Ah[m][k0] = h4; *(short4v*)&Al[m][k0] = l4;
        }
        if (tid < 64) { btl[tid] = Bst[(size_t)t*64 + tid]; itl[tid] = inp[(size_t)t*64 + tid]; }
        if (s + 1 < CH) {
            const float4* Ap = (const float4*)(Ag + (size_t)(t+1) * 4096);
#pragma unroll
            for (int q = 0; q < 4; ++q) pre[q] = Ap[tid + q * 256];
        }
        __syncthreads();

#pragma unroll
        for (int ni = 0; ni < 4; ++ni) {
            float ib = itl[16*ni + l15];
#pragma unroll
            for (int r = 0; r < 4; ++r) acc[ni][r] = btl[16*w + 4*quad + r] * ib;
        }
#pragma unroll
        for (int kc = 0; kc < 2; ++kc) {
            int ko = 32*kc + 8*quad;
            short8 aH = *(const short8*)&Ah[16*w + l15][ko];
            short8 aL = *(const short8*)&Al[16*w + l15][ko];
#pragma unroll
            for (int ni = 0; ni < 4; ++ni) {
                int n = 16*ni + l15;
                short8 xH = *(const short8*)&XBh[n][ko];
                short8 xL = *(const short8*)&XBl[n][ko];
                acc[ni] = mfma_bf16(aH, xH, acc[ni]);
                acc[ni] = mfma_bf16(aH, xL, acc[ni]);
                acc[ni] = mfma_bf16(aL, xH, acc[ni]);
            }
        }
        __syncthreads();
#pragma unroll
        for (int ni = 0; ni < 4; ++ni) {
            int cc = 16*ni + l15, r0 = 16*w + 4*quad;
            *(floatx4*)(out + (size_t)t*4096 + cc*64 + r0) = acc[ni];   // out[t][b][n0..3]
            if (s + 1 < CH) {
                short4v h4, l4;
#pragma unroll
                for (int r=0;r<4;++r){short hh,ll;split_bf16(acc[ni][r],hh,ll);h4[r]=hh;l4[r]=ll;}
                *(short4v*)&XBh[cc][r0] = h4; *(short4v*)&XBl[cc][r0] = l4;
            }
        }
    }
}

extern "C" void kernel_launch(void* const* d_in, const int* in_sizes, int n_in,
                              void* d_out, int out_size, void* d_ws, size_t ws_size,
                              hipStream_t stream)
{
    const float* inp = (const float*)d_in[0];   // (L, B)
    const float* A   = (const float*)d_in[1];   // (L, N, N)
    const float* Bst = (const float*)d_in[2];   // (L, N)
    float* out = (float*)d_out;                  // (L, B, N) = 16M floats
    float* ws  = (float*)d_ws;                   // 16 MB used

    // buf0 in ws, buf1 in the front 16 MB of d_out (legal scratch: phase3
    // fully rewrites d_out afterwards, and reads only ws).
    float* PT0 = ws;
    float* VT0 = ws + (size_t)CN * 4096;
    float* PT1 = out;
    float* VT1 = out + (size_t)CN * 4096;

    hippo_phase1<<<CN, 256, 0, stream>>>(inp, A, Bst, PT1, VT1);

    // 9 rounds, src starts at buf1 so the final (r=8, even) result lands in buf0 (ws).
    const float* ps = PT1; const float* vs = VT1;
    float* pd = PT0; float* vd = VT0;
    for (int r = 0; r < 9; ++r) {
        hippo_scan<<<CN, 256, 0, stream>>>(ps, vs, pd, vd, 1 << r, (r < 8) ? 1 : 0);
        const float* tp = pd; const float* tv = vd;
        pd = (float*)ps; vd = (float*)vs;
        ps = tp; vs = tv;
    }

    hippo_phase3<<<CN, 256, 0, stream>>>(inp, A, Bst, VT0, out);
}